// Round 1
// baseline (1522.401 us; speedup 1.0000x reference)
//
#include <hip/hip_runtime.h>
#include <math.h>

// BatchLossFunction: B=2048, P=197 (drop token 0 -> 196), D=768.
// loss = sum over (b,p) of -log(1-|sigmoid(1-cos(pt[b,p+1],ot[b])) - gt/255|)
//        * (gt/255*GAMMA + 1), divided by B.

#define GAMMA_C 3.4f
#define EPS_C   1e-8f
#define D_F4    192   // 768 floats = 192 float4
#define P_KEEP  196
#define P_FULL  197

// block = 256 threads (4 waves), one block per batch element b.
// Wave w handles p = w, w+4, ... (49 rows). out_text[b] fragment cached in
// registers across the whole loop. All loads are lane-contiguous float4.
__global__ __launch_bounds__(256, 8) void loss_main(
    const float* __restrict__ pt,      // (B,197,768)
    const float* __restrict__ ot,      // (B,768)
    const float* __restrict__ gt,      // (B,196)
    float* __restrict__ partials)      // (B,)
{
    const int b    = blockIdx.x;
    const int tid  = threadIdx.x;
    const int lane = tid & 63;
    const int wave = tid >> 6;         // 0..3

    // ---- out_text fragment: lane gets float4s {lane, lane+64, lane+128} ----
    const float4* otr = (const float4*)(ot + (size_t)b * 768);
    const float4 o0 = otr[lane];
    const float4 o1 = otr[lane + 64];
    const float4 o2 = otr[lane + 128];

    float osq = o0.x*o0.x + o0.y*o0.y + o0.z*o0.z + o0.w*o0.w
              + o1.x*o1.x + o1.y*o1.y + o1.z*o1.z + o1.w*o1.w
              + o2.x*o2.x + o2.y*o2.y + o2.z*o2.z + o2.w*o2.w;
    #pragma unroll
    for (int off = 32; off; off >>= 1) osq += __shfl_xor(osq, off, 64);
    const float ot_n     = fmaxf(sqrtf(osq), EPS_C);
    const float inv_ot_n = 1.0f / ot_n;

    const float* gtb = gt + (size_t)b * P_KEEP;

    float wsum = 0.0f;
    for (int p = wave; p < P_KEEP; p += 4) {
        const float4* ar =
            (const float4*)(pt + ((size_t)b * P_FULL + 1 + (size_t)p) * 768);
        const float4 a0 = ar[lane];
        const float4 a1 = ar[lane + 64];
        const float4 a2 = ar[lane + 128];

        float dot = a0.x*o0.x + a0.y*o0.y + a0.z*o0.z + a0.w*o0.w
                  + a1.x*o1.x + a1.y*o1.y + a1.z*o1.z + a1.w*o1.w
                  + a2.x*o2.x + a2.y*o2.y + a2.z*o2.z + a2.w*o2.w;
        float sq  = a0.x*a0.x + a0.y*a0.y + a0.z*a0.z + a0.w*a0.w
                  + a1.x*a1.x + a1.y*a1.y + a1.z*a1.z + a1.w*a1.w
                  + a2.x*a2.x + a2.y*a2.y + a2.z*a2.z + a2.w*a2.w;
        #pragma unroll
        for (int off = 32; off; off >>= 1) {
            dot += __shfl_xor(dot, off, 64);
            sq  += __shfl_xor(sq,  off, 64);
        }
        const float pt_n = fmaxf(sqrtf(sq), EPS_C);
        const float cosv = dot / pt_n * inv_ot_n;
        // sigmoid(1 - cos)
        const float vec  = 1.0f / (1.0f + expf(cosv - 1.0f));
        const float gtv  = gtb[p] * (1.0f / 255.0f);
        const float diff = fabsf(vec - gtv);
        const float term = -logf(1.0f - diff) * (gtv * GAMMA_C + 1.0f);
        wsum += term;
    }

    __shared__ float ws4[4];
    if (lane == 0) ws4[wave] = wsum;
    __syncthreads();
    if (tid == 0) partials[b] = (ws4[0] + ws4[1]) + (ws4[2] + ws4[3]);
}

__global__ __launch_bounds__(256) void loss_reduce(
    const float* __restrict__ partials, float* __restrict__ out, int B)
{
    __shared__ float s[256];
    const int tid = threadIdx.x;
    float v = 0.0f;
    for (int i = tid; i < B; i += 256) v += partials[i];
    s[tid] = v;
    __syncthreads();
    #pragma unroll
    for (int off = 128; off; off >>= 1) {
        if (tid < off) s[tid] += s[tid + off];
        __syncthreads();
    }
    if (tid == 0) out[0] = s[0] / (float)B;
}

extern "C" void kernel_launch(void* const* d_in, const int* in_sizes, int n_in,
                              void* d_out, int out_size, void* d_ws, size_t ws_size,
                              hipStream_t stream) {
    const float* pt = (const float*)d_in[0];   // (B,197,768)
    const float* ot = (const float*)d_in[1];   // (B,768)
    const float* gt = (const float*)d_in[2];   // (B,14,14)
    float* out      = (float*)d_out;           // scalar
    float* partials = (float*)d_ws;            // B floats

    const int B = in_sizes[1] / 768;           // 2048

    loss_main<<<B, 256, 0, stream>>>(pt, ot, gt, partials);
    loss_reduce<<<1, 256, 0, stream>>>(partials, out, B);
}